// Round 2
// baseline (1142.953 us; speedup 1.0000x reference)
//
#include <hip/hip_runtime.h>

// ---------------------------------------------------------------------------
// MultiHeadAttention: B=2, S=2048, D=1024, H=16, DEPTH=64
// out  = (2, 2047, 1024) fp32   att = (2, 16, 2047, 2047) fp32
// bf16x3 split MFMA for Q/K path; plain bf16 for V/O path.
// R2: attn reads K/V MFMA fragments DIRECTLY from global (L1/L2-resident) --
//     no LDS staging, no barriers, LDS = Ps only (9KB).  QKV projections
//     merged into one grid.z=3 launch; weights (B operand) read direct from
//     L2, only the A stream staged via global_load_lds.
// ---------------------------------------------------------------------------

typedef __attribute__((ext_vector_type(8))) short bf16x8;
typedef __attribute__((ext_vector_type(4))) float f32x4;

#define MFMA_BF16(A, B, C) __builtin_amdgcn_mfma_f32_16x16x32_bf16(A, B, C, 0, 0, 0)

__device__ __forceinline__ short f2bf(float x) {
    unsigned u = __float_as_uint(x);
    u = u + 0x7FFFu + ((u >> 16) & 1u);   // RNE
    return (short)(u >> 16);
}
__device__ __forceinline__ float bf2f(short s) {
    return __uint_as_float(((unsigned)(unsigned short)s) << 16);
}
__device__ __forceinline__ int imin(int a, int b) { return a < b ? a : b; }

// scores are pre-scaled by log2(e)/8, so softmax exp == exp2
__device__ __forceinline__ float fexp2(float x) {
#if __has_builtin(__builtin_amdgcn_exp2f)
    return __builtin_amdgcn_exp2f(x);
#else
    return __expf(x * 0.69314718055994531f);
#endif
}

// async global->LDS, 16B per lane; lds ptr per-lane = wave base + lane*16
__device__ __forceinline__ void dma16(const short* g, short* l) {
    __builtin_amdgcn_global_load_lds(
        (const __attribute__((address_space(1))) unsigned int*)g,
        (__attribute__((address_space(3))) unsigned int*)l, 16, 0, 0);
}

// ---------------------------------------------------------------------------
// Transpose 1024x1024 W -> T[n][k] = W[k][n], split into bf16 hi (+ opt lo)
// ---------------------------------------------------------------------------
__global__ __launch_bounds__(256) void transpose_split_kernel(
    const float* __restrict__ W, short* __restrict__ Thi, short* __restrict__ Tlo) {
    __shared__ float tile[32][33];
    const int tx = threadIdx.x & 31, ty = threadIdx.x >> 5;
    const int k0 = blockIdx.x * 32, n0 = blockIdx.y * 32;
#pragma unroll
    for (int p = 0; p < 4; ++p)
        tile[ty + p * 8][tx] = W[(size_t)(k0 + ty + p * 8) * 1024 + n0 + tx];
    __syncthreads();
#pragma unroll
    for (int p = 0; p < 4; ++p) {
        int n = n0 + ty + p * 8, k = k0 + tx;
        float x = tile[tx][ty + p * 8];
        short h = f2bf(x);
        Thi[(size_t)n * 1024 + k] = h;
        if (Tlo) Tlo[(size_t)n * 1024 + k] = f2bf(x - bf2f(h));
    }
}

// ---------------------------------------------------------------------------
// fp32 -> bf16 hi (+ optional lo) elementwise split, 8 elems/thread
// ---------------------------------------------------------------------------
__global__ __launch_bounds__(256) void split_kernel(
    const float* __restrict__ X, short* __restrict__ Hi, short* __restrict__ Lo, int n8) {
    int idx = blockIdx.x * 256 + threadIdx.x;
    if (idx >= n8) return;
    float4 x0 = *((const float4*)X + (size_t)idx * 2);
    float4 x1 = *((const float4*)X + (size_t)idx * 2 + 1);
    float xs[8] = {x0.x, x0.y, x0.z, x0.w, x1.x, x1.y, x1.z, x1.w};
    bf16x8 hv, lv;
#pragma unroll
    for (int e = 0; e < 8; ++e) {
        short h = f2bf(xs[e]);
        hv[e] = h;
        lv[e] = f2bf(xs[e] - bf2f(h));
    }
    *(bf16x8*)&Hi[(size_t)idx * 8] = hv;
    if (Lo) *(bf16x8*)&Lo[(size_t)idx * 8] = lv;
}

// ---------------------------------------------------------------------------
// Merged Q/K/V projection GEMM.  blockIdx.z selects {Q,K,V}.
// C[M x 1024] = A[M x 1024] @ Bt^T + bias  (Bt[n][k] pre-transposed).
// Tile 128(M) x 64(N), BK=32, 256 thr / 4 waves, wave quadrant 64x32.
// A staged to LDS via global_load_lds (HBM stream); B (weights, 2MB,
// L2-resident) read as per-lane direct global fragments.
// Q,K: bf16 hi/lo split in + out (3x MFMA).  V: hi only.
// ---------------------------------------------------------------------------
__global__ __launch_bounds__(256) void gemm_qkv(
    const short* __restrict__ Qhi, const short* __restrict__ Qlo,
    const short* __restrict__ Khi, const short* __restrict__ Klo,
    const short* __restrict__ Vbf,
    const short* __restrict__ Wqh, const short* __restrict__ Wql,
    const short* __restrict__ Wkh, const short* __restrict__ Wkl,
    const short* __restrict__ Wvh,
    const float* __restrict__ bq, const float* __restrict__ bk,
    const float* __restrict__ bv, float qscale,
    short* __restrict__ QQh, short* __restrict__ QQl,
    short* __restrict__ KKh, short* __restrict__ KKl,
    short* __restrict__ VVo) {
    __shared__ __align__(16) short Ah[512 * 8];
    __shared__ __align__(16) short Al[512 * 8];

    const int z = blockIdx.z;
    const bool split = (z < 2);
    const short* Ahg = (z == 0) ? Qhi : ((z == 1) ? Khi : Vbf);
    const short* Alg = (z == 0) ? Qlo : Klo;          // unused for z==2
    const short* Bhg = (z == 0) ? Wqh : ((z == 1) ? Wkh : Wvh);
    const short* Blg = (z == 0) ? Wql : Wkl;          // unused for z==2
    const float* bias = (z == 0) ? bq : ((z == 1) ? bk : bv);
    const float scale = (z == 0) ? qscale : 1.0f;
    const int M = (z == 2) ? 4094 : 4096;
    short* Chi = (z == 0) ? QQh : ((z == 1) ? KKh : VVo);
    short* Clo = (z == 0) ? QQl : KKl;

    const int tid = threadIdx.x;
    const int w = tid >> 6, lane = tid & 63;
    const int quad = lane >> 4, l16 = lane & 15;
    const int m0 = blockIdx.y * 128, n0 = blockIdx.x * 64;
    const int row0 = (w & 1) * 64, col0 = (w >> 1) * 32;

    f32x4 acc[4][2];
#pragma unroll
    for (int mi = 0; mi < 4; ++mi)
#pragma unroll
        for (int ni = 0; ni < 2; ++ni) acc[mi][ni] = (f32x4){0.f, 0.f, 0.f, 0.f};

    const int a_gr = imin(m0 + (tid & 127), M - 1);

    for (int k0 = 0; k0 < 1024; k0 += 32) {
        __syncthreads();
#pragma unroll
        for (int p = 0; p < 2; ++p) {
            int idx = p * 256 + tid;
            int c = idx >> 7;
            const size_t go = (size_t)a_gr * 1024 + k0 + c * 8;
            dma16(Ahg + go, &Ah[idx * 8]);
            if (split) dma16(Alg + go, &Al[idx * 8]);
        }
        // B fragments direct from global (L2-resident weights)
        bf16x8 bfh[2], bfl[2];
#pragma unroll
        for (int ni = 0; ni < 2; ++ni) {
            const size_t bo = (size_t)(n0 + col0 + ni * 16 + l16) * 1024 + k0 + quad * 8;
            bfh[ni] = *(const bf16x8*)&Bhg[bo];
            if (split) bfl[ni] = *(const bf16x8*)&Blg[bo];
        }
        __syncthreads();

        bf16x8 af[4], afl[4];
#pragma unroll
        for (int mi = 0; mi < 4; ++mi) {
            int r = row0 + mi * 16 + l16;
            af[mi] = *(const bf16x8*)&Ah[(quad * 128 + r) * 8];
            if (split) afl[mi] = *(const bf16x8*)&Al[(quad * 128 + r) * 8];
        }
#pragma unroll
        for (int mi = 0; mi < 4; ++mi)
#pragma unroll
            for (int ni = 0; ni < 2; ++ni) {
                acc[mi][ni] = MFMA_BF16(af[mi], bfh[ni], acc[mi][ni]);
                if (split) {
                    acc[mi][ni] = MFMA_BF16(af[mi], bfl[ni], acc[mi][ni]);
                    acc[mi][ni] = MFMA_BF16(afl[mi], bfh[ni], acc[mi][ni]);
                }
            }
    }

#pragma unroll
    for (int ni = 0; ni < 2; ++ni) {
        int col = n0 + col0 + ni * 16 + l16;
        float bv_ = bias[col];
#pragma unroll
        for (int mi = 0; mi < 4; ++mi) {
#pragma unroll
            for (int r = 0; r < 4; ++r) {
                int row = m0 + row0 + mi * 16 + quad * 4 + r;
                if (row < M) {
                    float c = (acc[mi][ni][r] + bv_) * scale;
                    size_t off = (size_t)row * 1024 + col;
                    short hsv = f2bf(c);
                    Chi[off] = hsv;
                    if (split) Clo[off] = f2bf(c - bf2f(hsv));
                }
            }
        }
    }
}

// ---------------------------------------------------------------------------
// GEMM: C[M x 1024] = A[M x 1024] @ Bt^T + bias  (O-projection, fp32 out)
// ---------------------------------------------------------------------------
__global__ __launch_bounds__(256) void gemm_o(
    const short* __restrict__ Ahg, int M, const short* __restrict__ Bhg,
    const float* __restrict__ bias, float* __restrict__ Cf) {
    __shared__ __align__(16) short Ah[512 * 8];

    const int tid = threadIdx.x;
    const int w = tid >> 6, lane = tid & 63;
    const int quad = lane >> 4, l16 = lane & 15;
    const int m0 = blockIdx.y * 128, n0 = blockIdx.x * 64;
    const int row0 = (w & 1) * 64, col0 = (w >> 1) * 32;

    f32x4 acc[4][2];
#pragma unroll
    for (int mi = 0; mi < 4; ++mi)
#pragma unroll
        for (int ni = 0; ni < 2; ++ni) acc[mi][ni] = (f32x4){0.f, 0.f, 0.f, 0.f};

    const int a_gr = imin(m0 + (tid & 127), M - 1);

    for (int k0 = 0; k0 < 1024; k0 += 32) {
        __syncthreads();
#pragma unroll
        for (int p = 0; p < 2; ++p) {
            int idx = p * 256 + tid;
            int c = idx >> 7;
            dma16(Ahg + (size_t)a_gr * 1024 + k0 + c * 8, &Ah[idx * 8]);
        }
        bf16x8 bfh[2];
#pragma unroll
        for (int ni = 0; ni < 2; ++ni) {
            const size_t bo = (size_t)(n0 + col0 + ni * 16 + l16) * 1024 + k0 + quad * 8;
            bfh[ni] = *(const bf16x8*)&Bhg[bo];
        }
        __syncthreads();

        bf16x8 af[4];
#pragma unroll
        for (int mi = 0; mi < 4; ++mi)
            af[mi] = *(const bf16x8*)&Ah[(quad * 128 + row0 + mi * 16 + l16) * 8];
#pragma unroll
        for (int mi = 0; mi < 4; ++mi)
#pragma unroll
            for (int ni = 0; ni < 2; ++ni)
                acc[mi][ni] = MFMA_BF16(af[mi], bfh[ni], acc[mi][ni]);
    }

#pragma unroll
    for (int ni = 0; ni < 2; ++ni) {
        int col = n0 + col0 + ni * 16 + l16;
        float bv_ = bias[col];
#pragma unroll
        for (int mi = 0; mi < 4; ++mi)
#pragma unroll
            for (int r = 0; r < 4; ++r) {
                int row = m0 + row0 + mi * 16 + quad * 4 + r;
                if (row < M) Cf[(size_t)row * 1024 + col] = acc[mi][ni][r] + bv_;
            }
    }
}

// ---------------------------------------------------------------------------
// VV [ (b*2047+seq)*1024 + h*64 + d ] -> VT [ ((b*16+h)*64+d)*2048 + seq ]
// (row pad to 2048; pad col written as 0)
// ---------------------------------------------------------------------------
__global__ __launch_bounds__(256) void transpose_v_kernel(
    const short* __restrict__ VV, short* __restrict__ VT) {
    __shared__ short t[64][72];
    const int tid = threadIdx.x;
    const int st = blockIdx.x & 31, bh = blockIdx.x >> 5;
    const int b = bh >> 4, h = bh & 15;
    const int s0 = st * 64;
    {
        int seq = s0 + (tid >> 2), d0 = (tid & 3) * 16;
        int seqc = imin(seq, 2046);
        const short* src = VV + ((size_t)(b * 2047 + seqc)) * 1024 + h * 64 + d0;
        bf16x8 v0 = *(const bf16x8*)src;
        bf16x8 v1 = *(const bf16x8*)(src + 8);
        bool ok = (seq <= 2046);
#pragma unroll
        for (int e = 0; e < 8; ++e) {
            t[d0 + e][tid >> 2] = ok ? v0[e] : (short)0;
            t[d0 + 8 + e][tid >> 2] = ok ? v1[e] : (short)0;
        }
    }
    __syncthreads();
    {
        int d = tid >> 2, sc2 = (tid & 3) * 16;
        bf16x8 o0, o1;
#pragma unroll
        for (int e = 0; e < 8; ++e) {
            o0[e] = t[d][sc2 + e];
            o1[e] = t[d][sc2 + 8 + e];
        }
        short* dst = VT + ((size_t)(bh * 64 + d)) * 2048 + s0 + sc2;
        *(bf16x8*)dst = o0;
        *(bf16x8*)(dst + 8) = o1;
    }
}

// ---------------------------------------------------------------------------
// Fused causal attention.  QQ pre-scaled by log2(e)/8 and split hi/lo.
// att[b,h,i,j] = softmax_{j<=i}( QQ[b,i+1,h]·KK[b,j,h] ), ctx -> CTX (bf16).
// Block = 64 q-rows (4 waves x 16).  64-key tiles, two passes.
// K/V fragments loaded DIRECTLY from global per lane (16 rows x 64B
// contiguous per wave; tiles are L1/L2-resident, 4 waves/block share them).
// No LDS staging, no barriers.  LDS = per-wave P buffer only (9KB).
// ---------------------------------------------------------------------------
__global__ __launch_bounds__(256) void attn_kernel(
    const short* __restrict__ QQh, const short* __restrict__ QQl,
    const short* __restrict__ KKh, const short* __restrict__ KKl,
    const short* __restrict__ VT,
    float* __restrict__ att, short* __restrict__ CTX) {
    __shared__ __align__(16) short Ps[4][16 * 72];

    const int tid = threadIdx.x;
    const int w = tid >> 6, lane = tid & 63;
    const int quad = lane >> 4, l16 = lane & 15;
    const int bx = blockIdx.x;
    const int qt = 31 - (bx >> 5);          // global work-descending order
    const int bh = bx & 31;
    const int h = bh & 15, b = bh >> 4;
    const int i0 = qt * 64;

    const int i_frag = i0 + w * 16 + l16;
    const int qrow = imin(i_frag + 1, 2047);
    const size_t qoff = ((size_t)(b * 2048 + qrow)) * 1024 + h * 64;
    const bf16x8 qh0 = *(const bf16x8*)&QQh[qoff + 0 + quad * 8];
    const bf16x8 qh1 = *(const bf16x8*)&QQh[qoff + 32 + quad * 8];
    const bf16x8 ql0 = *(const bf16x8*)&QQl[qoff + 0 + quad * 8];
    const bf16x8 ql1 = *(const bf16x8*)&QQl[qoff + 32 + quad * 8];

    const int i_max = imin(i0 + 63, 2046);
    const int jt_max = i_max >> 6;
    const int wave_imax = imin(i0 + w * 16 + 15, 2046);
    const int wave_jtmax = wave_imax >> 6;
    const int rowbase = i0 + w * 16 + quad * 4;

    // per-lane K-row base (row = j0 + s*16 + l16, dims quad*8 .. quad*8+7)
    const size_t kbase = ((size_t)(b * 2048 + l16)) * 1024 + h * 64 + quad * 8;
    // per-lane V-row base (row d = t*16 + l16, seq offset quad*8)
    const size_t vbase = ((size_t)(bh * 64 + l16)) * 2048 + quad * 8;

    float lsum[4] = {0.f, 0.f, 0.f, 0.f};

    // ---------------- PASS A: softmax denominators (K-hi only) --------------
    for (int jt = 0; jt <= wave_jtmax; ++jt) {
        const int j0 = jt * 64;
#pragma unroll
        for (int s = 0; s < 4; ++s) {
            f32x4 sc = (f32x4){0.f, 0.f, 0.f, 0.f};
            const size_t kr = kbase + (size_t)(j0 + s * 16) * 1024;
#pragma unroll
            for (int c = 0; c < 2; ++c) {
                bf16x8 kh = *(const bf16x8*)&KKh[kr + c * 32];
                sc = MFMA_BF16(c ? qh1 : qh0, kh, sc);
                sc = MFMA_BF16(c ? ql1 : ql0, kh, sc);
            }
            int j = j0 + s * 16 + l16;
#pragma unroll
            for (int r = 0; r < 4; ++r) {
                int i = rowbase + r;
                if (j <= i && i <= 2046) lsum[r] += fexp2(sc[r]);
            }
        }
    }
#pragma unroll
    for (int m = 1; m < 16; m <<= 1) {
#pragma unroll
        for (int r = 0; r < 4; ++r) lsum[r] += __shfl_xor(lsum[r], m, 64);
    }
    float linv[4];
#pragma unroll
    for (int r = 0; r < 4; ++r) linv[r] = 1.0f / lsum[r];

    f32x4 cacc[4];
#pragma unroll
    for (int t = 0; t < 4; ++t) cacc[t] = (f32x4){0.f, 0.f, 0.f, 0.f};

    // ---------------- PASS B: att writes + PV -------------------------------
    for (int jt = 0; jt <= jt_max; ++jt) {
        const int j0 = jt * 64;
        if (jt <= wave_jtmax) {
#pragma unroll
            for (int s = 0; s < 4; ++s) {
                f32x4 sc = (f32x4){0.f, 0.f, 0.f, 0.f};
                const size_t kr = kbase + (size_t)(j0 + s * 16) * 1024;
#pragma unroll
                for (int c = 0; c < 2; ++c) {
                    bf16x8 kh = *(const bf16x8*)&KKh[kr + c * 32];
                    bf16x8 kl = *(const bf16x8*)&KKl[kr + c * 32];
                    bf16x8 ah = c ? qh1 : qh0;
                    bf16x8 al = c ? ql1 : ql0;
                    sc = MFMA_BF16(ah, kh, sc);
                    sc = MFMA_BF16(ah, kl, sc);
                    sc = MFMA_BF16(al, kh, sc);
                }
                int j = j0 + s * 16 + l16;
#pragma unroll
                for (int r = 0; r < 4; ++r) {
                    int i = rowbase + r;
                    bool valid = (j <= i) && (i <= 2046);
                    float p = valid ? fexp2(sc[r]) * linv[r] : 0.0f;
                    if (i <= 2046 && j <= 2046)
                        att[((size_t)bh * 2047 + i) * 2047 + j] = p;
                    Ps[w][(quad * 4 + r) * 72 + s * 16 + l16] = f2bf(p);
                }
            }
#pragma unroll
            for (int c = 0; c < 2; ++c) {
                bf16x8 pa = *(const bf16x8*)&Ps[w][l16 * 72 + c * 32 + quad * 8];
#pragma unroll
                for (int t = 0; t < 4; ++t) {
                    bf16x8 vb = *(const bf16x8*)&VT[vbase + (size_t)t * 16 * 2048 +
                                                    j0 + c * 32];
                    cacc[t] = MFMA_BF16(pa, vb, cacc[t]);
                }
            }
        } else {
#pragma unroll
            for (int s = 0; s < 4; ++s) {
                int j = j0 + s * 16 + l16;
#pragma unroll
                for (int r = 0; r < 4; ++r) {
                    int i = rowbase + r;
                    if (i <= 2046 && j <= 2046)
                        att[((size_t)bh * 2047 + i) * 2047 + j] = 0.0f;
                }
            }
        }
    }

    // ctx -> CTX (bf16)
#pragma unroll
    for (int t = 0; t < 4; ++t) {
#pragma unroll
        for (int r = 0; r < 4; ++r) {
            int i = rowbase + r;
            if (i <= 2046)
                CTX[((size_t)(b * 2047 + i)) * 1024 + h * 64 + t * 16 + l16] = f2bf(cacc[t][r]);
        }
    }

    // zero tail: att cols beyond the block's causal tiles (float4 vectorized)
    const int js = (jt_max + 1) * 64;
    if (js < 2047) {
        const float4 z4 = {0.f, 0.f, 0.f, 0.f};
        for (int i = i0; i <= i_max; ++i) {
            const size_t base = (size_t)(bh * 2047 + i) * 2047;
            float* rowp = att + base;
            int aligned = js + (int)((4 - ((base + js) & 3)) & 3);
            if (aligned > 2047) aligned = 2047;
            for (int c = js + tid; c < aligned; c += 256) rowp[c] = 0.0f;
            int nv = (2047 - aligned) >> 2;
            for (int q = tid; q < nv; q += 256)
                *(float4*)(rowp + aligned + q * 4) = z4;
            for (int c = aligned + nv * 4 + tid; c < 2047; c += 256) rowp[c] = 0.0f;
        }
    }
}

// ---------------------------------------------------------------------------
extern "C" void kernel_launch(void* const* d_in, const int* in_sizes, int n_in,
                              void* d_out, int out_size, void* d_ws, size_t ws_size,
                              hipStream_t stream) {
    (void)in_sizes; (void)n_in; (void)out_size; (void)ws_size;
    const float* q  = (const float*)d_in[0];
    const float* k  = (const float*)d_in[1];
    const float* v  = (const float*)d_in[2];
    const float* Wq = (const float*)d_in[4];
    const float* bq = (const float*)d_in[5];
    const float* Wk = (const float*)d_in[6];
    const float* bk = (const float*)d_in[7];
    const float* Wv = (const float*)d_in[8];
    const float* bv = (const float*)d_in[9];
    const float* Wo = (const float*)d_in[10];
    const float* bo = (const float*)d_in[11];

    float* out = (float*)d_out;                     // 2*2047*1024
    float* att = out + (size_t)2 * 2047 * 1024;     // 2*16*2047*2047

    char* ws = (char*)d_ws;
    size_t off = 0;
    auto alloc = [&](size_t bytes) -> void* {
        void* p = ws + off;
        off += (bytes + 255) & ~(size_t)255;
        return p;
    };
    short* Wqt_h = (short*)alloc((size_t)1024 * 1024 * 2);
    short* Wqt_l = (short*)alloc((size_t)1024 * 1024 * 2);
    short* Wkt_h = (short*)alloc((size_t)1024 * 1024 * 2);
    short* Wkt_l = (short*)alloc((size_t)1024 * 1024 * 2);
    short* Wvt_h = (short*)alloc((size_t)1024 * 1024 * 2);
    short* Wot_h = (short*)alloc((size_t)1024 * 1024 * 2);
    short* Qhi = (short*)alloc((size_t)4096 * 1024 * 2);
    short* Qlo = (short*)alloc((size_t)4096 * 1024 * 2);
    short* Khi = (short*)alloc((size_t)4096 * 1024 * 2);
    short* Klo = (short*)alloc((size_t)4096 * 1024 * 2);
    short* Vbf = (short*)alloc((size_t)4096 * 1024 * 2);
    short* QQh = (short*)alloc((size_t)4096 * 1024 * 2);
    short* QQl = (short*)alloc((size_t)4096 * 1024 * 2);
    short* KKh = (short*)alloc((size_t)4096 * 1024 * 2);
    short* KKl = (short*)alloc((size_t)4096 * 1024 * 2);
    short* VV  = (short*)alloc((size_t)4096 * 1024 * 2);
    short* VT  = (short*)alloc((size_t)2048 * 2048 * 2 * 2);
    short* CTX = (short*)alloc((size_t)4096 * 1024 * 2);

    dim3 tgrid(32, 32);
    transpose_split_kernel<<<tgrid, 256, 0, stream>>>(Wq, Wqt_h, Wqt_l);
    transpose_split_kernel<<<tgrid, 256, 0, stream>>>(Wk, Wkt_h, Wkt_l);
    transpose_split_kernel<<<tgrid, 256, 0, stream>>>(Wv, Wvt_h, nullptr);
    transpose_split_kernel<<<tgrid, 256, 0, stream>>>(Wo, Wot_h, nullptr);

    split_kernel<<<2048, 256, 0, stream>>>(q, Qhi, Qlo, 4096 * 1024 / 8);
    split_kernel<<<2048, 256, 0, stream>>>(k, Khi, Klo, 4096 * 1024 / 8);
    split_kernel<<<2047, 256, 0, stream>>>(v, Vbf, nullptr, 4094 * 1024 / 8);

    // QQ scaled by log2(e)/8 so attention softmax can use native exp2.
    const float qscale = 0.125f * 1.44269504088896341f;
    gemm_qkv<<<dim3(16, 32, 3), 256, 0, stream>>>(
        Qhi, Qlo, Khi, Klo, Vbf, Wqt_h, Wqt_l, Wkt_h, Wkt_l, Wvt_h,
        bq, bk, bv, qscale, QQh, QQl, KKh, KKl, VV);

    transpose_v_kernel<<<dim3(32 * 32), 256, 0, stream>>>(VV, VT);

    attn_kernel<<<dim3(32 * 32), 256, 0, stream>>>(QQh, QQl, KKh, KKl, VT, att, CTX);

    gemm_o<<<dim3(16, 32), 256, 0, stream>>>(CTX, 4094, Wot_h, bo, out);
}

// Round 3
// 1001.673 us; speedup vs baseline: 1.1410x; 1.1410x over previous
//
#include <hip/hip_runtime.h>

// ---------------------------------------------------------------------------
// MultiHeadAttention: B=2, S=2048, D=1024, H=16, DEPTH=64
// out  = (2, 2047, 1024) fp32   att = (2, 16, 2047, 2047) fp32
// bf16x3 split MFMA for Q/K path; plain bf16 for V/O path.
// R3: attn back to LDS staging (R2 direct-load was latency-bound: MfmaUtil
//     5%, VALU 13%, HBM 22%).  128 q-rows/block (8 waves): staged bytes +
//     barriers per unit compute HALVED vs R0/R1.  Pass A double-buffers K-hi
//     through the idle Kl buffer (1 barrier/tile).  LDS 43KB, grid 512.
// ---------------------------------------------------------------------------

typedef __attribute__((ext_vector_type(8))) short bf16x8;
typedef __attribute__((ext_vector_type(4))) float f32x4;

#define MFMA_BF16(A, B, C) __builtin_amdgcn_mfma_f32_16x16x32_bf16(A, B, C, 0, 0, 0)

__device__ __forceinline__ short f2bf(float x) {
    unsigned u = __float_as_uint(x);
    u = u + 0x7FFFu + ((u >> 16) & 1u);   // RNE
    return (short)(u >> 16);
}
__device__ __forceinline__ float bf2f(short s) {
    return __uint_as_float(((unsigned)(unsigned short)s) << 16);
}
__device__ __forceinline__ int imin(int a, int b) { return a < b ? a : b; }

// scores are pre-scaled by log2(e)/8, so softmax exp == exp2
__device__ __forceinline__ float fexp2(float x) {
#if __has_builtin(__builtin_amdgcn_exp2f)
    return __builtin_amdgcn_exp2f(x);
#else
    return __expf(x * 0.69314718055994531f);
#endif
}

// async global->LDS, 16B per lane; lds ptr per-lane = wave base + lane*16
__device__ __forceinline__ void dma16(const short* g, short* l) {
    __builtin_amdgcn_global_load_lds(
        (const __attribute__((address_space(1))) unsigned int*)g,
        (__attribute__((address_space(3))) unsigned int*)l, 16, 0, 0);
}

// ---------------------------------------------------------------------------
// Transpose 1024x1024 W -> T[n][k] = W[k][n], split into bf16 hi (+ opt lo)
// ---------------------------------------------------------------------------
__global__ __launch_bounds__(256) void transpose_split_kernel(
    const float* __restrict__ W, short* __restrict__ Thi, short* __restrict__ Tlo) {
    __shared__ float tile[32][33];
    const int tx = threadIdx.x & 31, ty = threadIdx.x >> 5;
    const int k0 = blockIdx.x * 32, n0 = blockIdx.y * 32;
#pragma unroll
    for (int p = 0; p < 4; ++p)
        tile[ty + p * 8][tx] = W[(size_t)(k0 + ty + p * 8) * 1024 + n0 + tx];
    __syncthreads();
#pragma unroll
    for (int p = 0; p < 4; ++p) {
        int n = n0 + ty + p * 8, k = k0 + tx;
        float x = tile[tx][ty + p * 8];
        short h = f2bf(x);
        Thi[(size_t)n * 1024 + k] = h;
        if (Tlo) Tlo[(size_t)n * 1024 + k] = f2bf(x - bf2f(h));
    }
}

// ---------------------------------------------------------------------------
// fp32 -> bf16 hi (+ optional lo) elementwise split, 8 elems/thread
// ---------------------------------------------------------------------------
__global__ __launch_bounds__(256) void split_kernel(
    const float* __restrict__ X, short* __restrict__ Hi, short* __restrict__ Lo, int n8) {
    int idx = blockIdx.x * 256 + threadIdx.x;
    if (idx >= n8) return;
    float4 x0 = *((const float4*)X + (size_t)idx * 2);
    float4 x1 = *((const float4*)X + (size_t)idx * 2 + 1);
    float xs[8] = {x0.x, x0.y, x0.z, x0.w, x1.x, x1.y, x1.z, x1.w};
    bf16x8 hv, lv;
#pragma unroll
    for (int e = 0; e < 8; ++e) {
        short h = f2bf(xs[e]);
        hv[e] = h;
        lv[e] = f2bf(xs[e] - bf2f(h));
    }
    *(bf16x8*)&Hi[(size_t)idx * 8] = hv;
    if (Lo) *(bf16x8*)&Lo[(size_t)idx * 8] = lv;
}

// ---------------------------------------------------------------------------
// Merged Q/K/V projection GEMM.  blockIdx.z selects {Q,K,V}.
// C[M x 1024] = A[M x 1024] @ Bt^T + bias  (Bt[n][k] pre-transposed).
// Tile 128(M) x 64(N), BK=32, 256 thr / 4 waves, wave quadrant 64x32.
// A staged to LDS via global_load_lds (HBM stream); B (weights, 2MB,
// L2-resident) read as per-lane direct global fragments.
// Q,K: bf16 hi/lo split in + out (3x MFMA).  V: hi only.
// ---------------------------------------------------------------------------
__global__ __launch_bounds__(256) void gemm_qkv(
    const short* __restrict__ Qhi, const short* __restrict__ Qlo,
    const short* __restrict__ Khi, const short* __restrict__ Klo,
    const short* __restrict__ Vbf,
    const short* __restrict__ Wqh, const short* __restrict__ Wql,
    const short* __restrict__ Wkh, const short* __restrict__ Wkl,
    const short* __restrict__ Wvh,
    const float* __restrict__ bq, const float* __restrict__ bk,
    const float* __restrict__ bv, float qscale,
    short* __restrict__ QQh, short* __restrict__ QQl,
    short* __restrict__ KKh, short* __restrict__ KKl,
    short* __restrict__ VVo) {
    __shared__ __align__(16) short Ah[512 * 8];
    __shared__ __align__(16) short Al[512 * 8];

    const int z = blockIdx.z;
    const bool split = (z < 2);
    const short* Ahg = (z == 0) ? Qhi : ((z == 1) ? Khi : Vbf);
    const short* Alg = (z == 0) ? Qlo : Klo;          // unused for z==2
    const short* Bhg = (z == 0) ? Wqh : ((z == 1) ? Wkh : Wvh);
    const short* Blg = (z == 0) ? Wql : Wkl;          // unused for z==2
    const float* bias = (z == 0) ? bq : ((z == 1) ? bk : bv);
    const float scale = (z == 0) ? qscale : 1.0f;
    const int M = (z == 2) ? 4094 : 4096;
    short* Chi = (z == 0) ? QQh : ((z == 1) ? KKh : VVo);
    short* Clo = (z == 0) ? QQl : KKl;

    const int tid = threadIdx.x;
    const int w = tid >> 6, lane = tid & 63;
    const int quad = lane >> 4, l16 = lane & 15;
    const int m0 = blockIdx.y * 128, n0 = blockIdx.x * 64;
    const int row0 = (w & 1) * 64, col0 = (w >> 1) * 32;

    f32x4 acc[4][2];
#pragma unroll
    for (int mi = 0; mi < 4; ++mi)
#pragma unroll
        for (int ni = 0; ni < 2; ++ni) acc[mi][ni] = (f32x4){0.f, 0.f, 0.f, 0.f};

    const int a_gr = imin(m0 + (tid & 127), M - 1);

    for (int k0 = 0; k0 < 1024; k0 += 32) {
        __syncthreads();
#pragma unroll
        for (int p = 0; p < 2; ++p) {
            int idx = p * 256 + tid;
            int c = idx >> 7;
            const size_t go = (size_t)a_gr * 1024 + k0 + c * 8;
            dma16(Ahg + go, &Ah[idx * 8]);
            if (split) dma16(Alg + go, &Al[idx * 8]);
        }
        // B fragments direct from global (L2-resident weights)
        bf16x8 bfh[2], bfl[2];
#pragma unroll
        for (int ni = 0; ni < 2; ++ni) {
            const size_t bo = (size_t)(n0 + col0 + ni * 16 + l16) * 1024 + k0 + quad * 8;
            bfh[ni] = *(const bf16x8*)&Bhg[bo];
            if (split) bfl[ni] = *(const bf16x8*)&Blg[bo];
        }
        __syncthreads();

        bf16x8 af[4], afl[4];
#pragma unroll
        for (int mi = 0; mi < 4; ++mi) {
            int r = row0 + mi * 16 + l16;
            af[mi] = *(const bf16x8*)&Ah[(quad * 128 + r) * 8];
            if (split) afl[mi] = *(const bf16x8*)&Al[(quad * 128 + r) * 8];
        }
#pragma unroll
        for (int mi = 0; mi < 4; ++mi)
#pragma unroll
            for (int ni = 0; ni < 2; ++ni) {
                acc[mi][ni] = MFMA_BF16(af[mi], bfh[ni], acc[mi][ni]);
                if (split) {
                    acc[mi][ni] = MFMA_BF16(af[mi], bfl[ni], acc[mi][ni]);
                    acc[mi][ni] = MFMA_BF16(afl[mi], bfh[ni], acc[mi][ni]);
                }
            }
    }

#pragma unroll
    for (int ni = 0; ni < 2; ++ni) {
        int col = n0 + col0 + ni * 16 + l16;
        float bv_ = bias[col];
#pragma unroll
        for (int mi = 0; mi < 4; ++mi) {
#pragma unroll
            for (int r = 0; r < 4; ++r) {
                int row = m0 + row0 + mi * 16 + quad * 4 + r;
                if (row < M) {
                    float c = (acc[mi][ni][r] + bv_) * scale;
                    size_t off = (size_t)row * 1024 + col;
                    short hsv = f2bf(c);
                    Chi[off] = hsv;
                    if (split) Clo[off] = f2bf(c - bf2f(hsv));
                }
            }
        }
    }
}

// ---------------------------------------------------------------------------
// GEMM: C[M x 1024] = A[M x 1024] @ Bt^T + bias  (O-projection, fp32 out)
// ---------------------------------------------------------------------------
__global__ __launch_bounds__(256) void gemm_o(
    const short* __restrict__ Ahg, int M, const short* __restrict__ Bhg,
    const float* __restrict__ bias, float* __restrict__ Cf) {
    __shared__ __align__(16) short Ah[512 * 8];

    const int tid = threadIdx.x;
    const int w = tid >> 6, lane = tid & 63;
    const int quad = lane >> 4, l16 = lane & 15;
    const int m0 = blockIdx.y * 128, n0 = blockIdx.x * 64;
    const int row0 = (w & 1) * 64, col0 = (w >> 1) * 32;

    f32x4 acc[4][2];
#pragma unroll
    for (int mi = 0; mi < 4; ++mi)
#pragma unroll
        for (int ni = 0; ni < 2; ++ni) acc[mi][ni] = (f32x4){0.f, 0.f, 0.f, 0.f};

    const int a_gr = imin(m0 + (tid & 127), M - 1);

    for (int k0 = 0; k0 < 1024; k0 += 32) {
        __syncthreads();
#pragma unroll
        for (int p = 0; p < 2; ++p) {
            int idx = p * 256 + tid;
            int c = idx >> 7;
            dma16(Ahg + (size_t)a_gr * 1024 + k0 + c * 8, &Ah[idx * 8]);
        }
        bf16x8 bfh[2];
#pragma unroll
        for (int ni = 0; ni < 2; ++ni) {
            const size_t bo = (size_t)(n0 + col0 + ni * 16 + l16) * 1024 + k0 + quad * 8;
            bfh[ni] = *(const bf16x8*)&Bhg[bo];
        }
        __syncthreads();

        bf16x8 af[4];
#pragma unroll
        for (int mi = 0; mi < 4; ++mi)
            af[mi] = *(const bf16x8*)&Ah[(quad * 128 + row0 + mi * 16 + l16) * 8];
#pragma unroll
        for (int mi = 0; mi < 4; ++mi)
#pragma unroll
            for (int ni = 0; ni < 2; ++ni)
                acc[mi][ni] = MFMA_BF16(af[mi], bfh[ni], acc[mi][ni]);
    }

#pragma unroll
    for (int ni = 0; ni < 2; ++ni) {
        int col = n0 + col0 + ni * 16 + l16;
        float bv_ = bias[col];
#pragma unroll
        for (int mi = 0; mi < 4; ++mi)
#pragma unroll
            for (int r = 0; r < 4; ++r) {
                int row = m0 + row0 + mi * 16 + quad * 4 + r;
                if (row < M) Cf[(size_t)row * 1024 + col] = acc[mi][ni][r] + bv_;
            }
    }
}

// ---------------------------------------------------------------------------
// VV [ (b*2047+seq)*1024 + h*64 + d ] -> VT [ ((b*16+h)*64+d)*2048 + seq ]
// (row pad to 2048; pad col written as 0)
// ---------------------------------------------------------------------------
__global__ __launch_bounds__(256) void transpose_v_kernel(
    const short* __restrict__ VV, short* __restrict__ VT) {
    __shared__ short t[64][72];
    const int tid = threadIdx.x;
    const int st = blockIdx.x & 31, bh = blockIdx.x >> 5;
    const int b = bh >> 4, h = bh & 15;
    const int s0 = st * 64;
    {
        int seq = s0 + (tid >> 2), d0 = (tid & 3) * 16;
        int seqc = imin(seq, 2046);
        const short* src = VV + ((size_t)(b * 2047 + seqc)) * 1024 + h * 64 + d0;
        bf16x8 v0 = *(const bf16x8*)src;
        bf16x8 v1 = *(const bf16x8*)(src + 8);
        bool ok = (seq <= 2046);
#pragma unroll
        for (int e = 0; e < 8; ++e) {
            t[d0 + e][tid >> 2] = ok ? v0[e] : (short)0;
            t[d0 + 8 + e][tid >> 2] = ok ? v1[e] : (short)0;
        }
    }
    __syncthreads();
    {
        int d = tid >> 2, sc2 = (tid & 3) * 16;
        bf16x8 o0, o1;
#pragma unroll
        for (int e = 0; e < 8; ++e) {
            o0[e] = t[d][sc2 + e];
            o1[e] = t[d][sc2 + 8 + e];
        }
        short* dst = VT + ((size_t)(bh * 64 + d)) * 2048 + s0 + sc2;
        *(bf16x8*)dst = o0;
        *(bf16x8*)(dst + 8) = o1;
    }
}

// ---------------------------------------------------------------------------
// Fused causal attention.  QQ pre-scaled by log2(e)/8 and split hi/lo.
// att[b,h,i,j] = softmax_{j<=i}( QQ[b,i+1,h]·KK[b,j,h] ), ctx -> CTX (bf16).
// 128 q-rows / block (8 waves x 16 rows).  64-key tiles, two passes.
// Pass A (denominators): K-hi only, double-buffered through Kh/Kl space,
// 1 barrier/tile.  Pass B: hi/lo K + V staged single-buffered, 2 barriers.
// Staged bytes + barriers per unit compute are HALF of the 64-row version.
// LDS 43KB -> 512-thread blocks, 512 blocks (all resident, ~16 waves/CU).
// ---------------------------------------------------------------------------
__global__ __launch_bounds__(512) void attn_kernel(
    const short* __restrict__ QQh, const short* __restrict__ QQl,
    const short* __restrict__ KKh, const short* __restrict__ KKl,
    const short* __restrict__ VT,
    float* __restrict__ att, short* __restrict__ CTX) {
    __shared__ __align__(16) short Kh[512 * 8];   // [cc=8][key=64]
    __shared__ __align__(16) short Kl[512 * 8];   // pass A: 2nd buffer
    __shared__ __align__(16) short Vt[512 * 8];   // [kc=8][d=64]
    __shared__ __align__(16) short Ps[8][16 * 72];

    const int tid = threadIdx.x;
    const int w = tid >> 6, lane = tid & 63;
    const int quad = lane >> 4, l16 = lane & 15;
    const int bx = blockIdx.x;
    const int qt = 15 - (bx >> 5);          // heavy q-tiles first
    const int bh = bx & 31;
    const int h = bh & 15, b = bh >> 4;
    const int i0 = qt * 128;

    const int i_frag = i0 + w * 16 + l16;
    const int qrow = imin(i_frag + 1, 2047);
    const size_t qoff = ((size_t)(b * 2048 + qrow)) * 1024 + h * 64;
    const bf16x8 qh0 = *(const bf16x8*)&QQh[qoff + 0 + quad * 8];
    const bf16x8 qh1 = *(const bf16x8*)&QQh[qoff + 32 + quad * 8];
    const bf16x8 ql0 = *(const bf16x8*)&QQl[qoff + 0 + quad * 8];
    const bf16x8 ql1 = *(const bf16x8*)&QQl[qoff + 32 + quad * 8];

    const int i_max = imin(i0 + 127, 2046);
    const int jt_max = i_max >> 6;
    const int wave_imax = imin(i0 + w * 16 + 15, 2046);
    const int rowbase = i0 + w * 16 + quad * 4;

    const int dk = tid & 63;     // key (K) / dim (V) row
    const int dc = tid >> 6;     // 8-elem chunk

    float lsum[4] = {0.f, 0.f, 0.f, 0.f};

    // ---------------- PASS A: softmax denominators (K-hi only) --------------
    // double-buffered through Kh/Kl space, 1 barrier per tile
    auto stA = [&](int jt, short* dst) {
        dma16(KKh + ((size_t)(b * 2048 + jt * 64 + dk)) * 1024 + h * 64 + dc * 8,
              &dst[tid * 8]);
    };
    stA(0, Kh);
    __syncthreads();
    int cur = 0;
    for (int jt = 0; jt <= jt_max; ++jt) {
        if (jt < jt_max) stA(jt + 1, cur ? Kh : Kl);
        if (jt * 64 <= wave_imax) {
            const short* Kc = cur ? Kl : Kh;
#pragma unroll
            for (int s = 0; s < 4; ++s) {
                f32x4 sc = (f32x4){0.f, 0.f, 0.f, 0.f};
#pragma unroll
                for (int c = 0; c < 2; ++c) {
                    bf16x8 kh = *(const bf16x8*)&Kc[((c * 4 + quad) * 64 + s * 16 + l16) * 8];
                    sc = MFMA_BF16(c ? qh1 : qh0, kh, sc);
                    sc = MFMA_BF16(c ? ql1 : ql0, kh, sc);
                }
                int j = jt * 64 + s * 16 + l16;
#pragma unroll
                for (int r = 0; r < 4; ++r) {
                    int i = rowbase + r;
                    if (j <= i && i <= 2046) lsum[r] += fexp2(sc[r]);
                }
            }
        }
        __syncthreads();
        cur ^= 1;
    }
#pragma unroll
    for (int m = 1; m < 16; m <<= 1) {
#pragma unroll
        for (int r = 0; r < 4; ++r) lsum[r] += __shfl_xor(lsum[r], m, 64);
    }
    float linv[4];
#pragma unroll
    for (int r = 0; r < 4; ++r) linv[r] = 1.0f / lsum[r];

    f32x4 cacc[4];
#pragma unroll
    for (int t = 0; t < 4; ++t) cacc[t] = (f32x4){0.f, 0.f, 0.f, 0.f};

    // ---------------- PASS B: att writes + PV -------------------------------
    for (int jt = 0; jt <= jt_max; ++jt) {
        const int j0 = jt * 64;
        __syncthreads();   // previous tile fully consumed
        {
            const size_t ko = ((size_t)(b * 2048 + j0 + dk)) * 1024 + h * 64 + dc * 8;
            dma16(KKh + ko, &Kh[tid * 8]);
            dma16(KKl + ko, &Kl[tid * 8]);
            dma16(VT + ((size_t)(bh * 64 + dk)) * 2048 + j0 + dc * 8, &Vt[tid * 8]);
        }
        __syncthreads();   // drain DMA
        if (j0 <= wave_imax) {
#pragma unroll
            for (int s = 0; s < 4; ++s) {
                f32x4 sc = (f32x4){0.f, 0.f, 0.f, 0.f};
#pragma unroll
                for (int c = 0; c < 2; ++c) {
                    const int ci = ((c * 4 + quad) * 64 + s * 16 + l16) * 8;
                    bf16x8 kh = *(const bf16x8*)&Kh[ci];
                    bf16x8 kl = *(const bf16x8*)&Kl[ci];
                    bf16x8 ah = c ? qh1 : qh0;
                    bf16x8 al = c ? ql1 : ql0;
                    sc = MFMA_BF16(ah, kh, sc);
                    sc = MFMA_BF16(ah, kl, sc);
                    sc = MFMA_BF16(al, kh, sc);
                }
                int j = j0 + s * 16 + l16;
#pragma unroll
                for (int r = 0; r < 4; ++r) {
                    int i = rowbase + r;
                    bool valid = (j <= i) && (i <= 2046);
                    float p = valid ? fexp2(sc[r]) * linv[r] : 0.0f;
                    if (i <= 2046 && j <= 2046)
                        att[((size_t)bh * 2047 + i) * 2047 + j] = p;
                    Ps[w][(quad * 4 + r) * 72 + s * 16 + l16] = f2bf(p);
                }
            }
#pragma unroll
            for (int c = 0; c < 2; ++c) {
                bf16x8 pa = *(const bf16x8*)&Ps[w][l16 * 72 + c * 32 + quad * 8];
#pragma unroll
                for (int t = 0; t < 4; ++t) {
                    bf16x8 vb = *(const bf16x8*)&Vt[((c * 4 + quad) * 64 + t * 16 + l16) * 8];
                    cacc[t] = MFMA_BF16(pa, vb, cacc[t]);
                }
            }
        } else {
#pragma unroll
            for (int s = 0; s < 4; ++s) {
                int j = j0 + s * 16 + l16;
#pragma unroll
                for (int r = 0; r < 4; ++r) {
                    int i = rowbase + r;
                    if (i <= 2046 && j <= 2046)
                        att[((size_t)bh * 2047 + i) * 2047 + j] = 0.0f;
                }
            }
        }
    }

    // ctx -> CTX (bf16)
#pragma unroll
    for (int t = 0; t < 4; ++t) {
#pragma unroll
        for (int r = 0; r < 4; ++r) {
            int i = rowbase + r;
            if (i <= 2046)
                CTX[((size_t)(b * 2047 + i)) * 1024 + h * 64 + t * 16 + l16] = f2bf(cacc[t][r]);
        }
    }

    // zero tail: att cols beyond the block's causal tiles (float4 vectorized)
    const int js = (jt_max + 1) * 64;
    if (js < 2047) {
        const float4 z4 = {0.f, 0.f, 0.f, 0.f};
        for (int i = i0; i <= i_max; ++i) {
            const size_t base = (size_t)(bh * 2047 + i) * 2047;
            float* rowp = att + base;
            int aligned = js + (int)((4 - ((base + js) & 3)) & 3);
            if (aligned > 2047) aligned = 2047;
            for (int c = js + tid; c < aligned; c += 512) rowp[c] = 0.0f;
            int nv = (2047 - aligned) >> 2;
            for (int q = tid; q < nv; q += 512)
                *(float4*)(rowp + aligned + q * 4) = z4;
            for (int c = aligned + nv * 4 + tid; c < 2047; c += 512) rowp[c] = 0.0f;
        }
    }
}

// ---------------------------------------------------------------------------
extern "C" void kernel_launch(void* const* d_in, const int* in_sizes, int n_in,
                              void* d_out, int out_size, void* d_ws, size_t ws_size,
                              hipStream_t stream) {
    (void)in_sizes; (void)n_in; (void)out_size; (void)ws_size;
    const float* q  = (const float*)d_in[0];
    const float* k  = (const float*)d_in[1];
    const float* v  = (const float*)d_in[2];
    const float* Wq = (const float*)d_in[4];
    const float* bq = (const float*)d_in[5];
    const float* Wk = (const float*)d_in[6];
    const float* bk = (const float*)d_in[7];
    const float* Wv = (const float*)d_in[8];
    const float* bv = (const float*)d_in[9];
    const float* Wo = (const float*)d_in[10];
    const float* bo = (const float*)d_in[11];

    float* out = (float*)d_out;                     // 2*2047*1024
    float* att = out + (size_t)2 * 2047 * 1024;     // 2*16*2047*2047

    char* ws = (char*)d_ws;
    size_t off = 0;
    auto alloc = [&](size_t bytes) -> void* {
        void* p = ws + off;
        off += (bytes + 255) & ~(size_t)255;
        return p;
    };
    short* Wqt_h = (short*)alloc((size_t)1024 * 1024 * 2);
    short* Wqt_l = (short*)alloc((size_t)1024 * 1024 * 2);
    short* Wkt_h = (short*)alloc((size_t)1024 * 1024 * 2);
    short* Wkt_l = (short*)alloc((size_t)1024 * 1024 * 2);
    short* Wvt_h = (short*)alloc((size_t)1024 * 1024 * 2);
    short* Wot_h = (short*)alloc((size_t)1024 * 1024 * 2);
    short* Qhi = (short*)alloc((size_t)4096 * 1024 * 2);
    short* Qlo = (short*)alloc((size_t)4096 * 1024 * 2);
    short* Khi = (short*)alloc((size_t)4096 * 1024 * 2);
    short* Klo = (short*)alloc((size_t)4096 * 1024 * 2);
    short* Vbf = (short*)alloc((size_t)4096 * 1024 * 2);
    short* QQh = (short*)alloc((size_t)4096 * 1024 * 2);
    short* QQl = (short*)alloc((size_t)4096 * 1024 * 2);
    short* KKh = (short*)alloc((size_t)4096 * 1024 * 2);
    short* KKl = (short*)alloc((size_t)4096 * 1024 * 2);
    short* VV  = (short*)alloc((size_t)4096 * 1024 * 2);
    short* VT  = (short*)alloc((size_t)2048 * 2048 * 2 * 2);
    short* CTX = (short*)alloc((size_t)4096 * 1024 * 2);

    dim3 tgrid(32, 32);
    transpose_split_kernel<<<tgrid, 256, 0, stream>>>(Wq, Wqt_h, Wqt_l);
    transpose_split_kernel<<<tgrid, 256, 0, stream>>>(Wk, Wkt_h, Wkt_l);
    transpose_split_kernel<<<tgrid, 256, 0, stream>>>(Wv, Wvt_h, nullptr);
    transpose_split_kernel<<<tgrid, 256, 0, stream>>>(Wo, Wot_h, nullptr);

    split_kernel<<<2048, 256, 0, stream>>>(q, Qhi, Qlo, 4096 * 1024 / 8);
    split_kernel<<<2048, 256, 0, stream>>>(k, Khi, Klo, 4096 * 1024 / 8);
    split_kernel<<<2047, 256, 0, stream>>>(v, Vbf, nullptr, 4094 * 1024 / 8);

    // QQ scaled by log2(e)/8 so attention softmax can use native exp2.
    const float qscale = 0.125f * 1.44269504088896341f;
    gemm_qkv<<<dim3(16, 32, 3), 256, 0, stream>>>(
        Qhi, Qlo, Khi, Klo, Vbf, Wqt_h, Wqt_l, Wkt_h, Wkt_l, Wvt_h,
        bq, bk, bv, qscale, QQh, QQl, KKh, KKl, VV);

    transpose_v_kernel<<<dim3(32 * 32), 256, 0, stream>>>(VV, VT);

    attn_kernel<<<dim3(16 * 32), 512, 0, stream>>>(QQh, QQl, KKh, KKl, VT, att, CTX);

    gemm_o<<<dim3(16, 32), 256, 0, stream>>>(CTX, 4094, Wot_h, bo, out);
}

// Round 4
// 959.752 us; speedup vs baseline: 1.1909x; 1.0437x over previous
//
#include <hip/hip_runtime.h>

// ---------------------------------------------------------------------------
// MultiHeadAttention: B=2, S=2048, D=1024, H=16, DEPTH=64
// out  = (2, 2047, 1024) fp32   att = (2, 16, 2047, 2047) fp32
// R4: projection GEMMs upgraded to 128x128 tile (4 waves x 64x64 quadrant,
//     4x4 frags = 16/48 MFMA per K-step per wave, both operands staged via
//     global_load_lds).  Weight transposes fused (grid.z=4); input splits
//     fused (grid.z=3).  Attention kernel unchanged from R3.
// ---------------------------------------------------------------------------

typedef __attribute__((ext_vector_type(8))) short bf16x8;
typedef __attribute__((ext_vector_type(4))) float f32x4;

#define MFMA_BF16(A, B, C) __builtin_amdgcn_mfma_f32_16x16x32_bf16(A, B, C, 0, 0, 0)

__device__ __forceinline__ short f2bf(float x) {
    unsigned u = __float_as_uint(x);
    u = u + 0x7FFFu + ((u >> 16) & 1u);   // RNE
    return (short)(u >> 16);
}
__device__ __forceinline__ float bf2f(short s) {
    return __uint_as_float(((unsigned)(unsigned short)s) << 16);
}
__device__ __forceinline__ int imin(int a, int b) { return a < b ? a : b; }

// scores are pre-scaled by log2(e)/8, so softmax exp == exp2
__device__ __forceinline__ float fexp2(float x) {
#if __has_builtin(__builtin_amdgcn_exp2f)
    return __builtin_amdgcn_exp2f(x);
#else
    return __expf(x * 0.69314718055994531f);
#endif
}

// async global->LDS, 16B per lane; lds ptr per-lane = wave base + lane*16
__device__ __forceinline__ void dma16(const short* g, short* l) {
    __builtin_amdgcn_global_load_lds(
        (const __attribute__((address_space(1))) unsigned int*)g,
        (__attribute__((address_space(3))) unsigned int*)l, 16, 0, 0);
}

// ---------------------------------------------------------------------------
// Fused weight transposes: z selects {Wq,Wk,Wv,Wo}.
// T[n][k] = W[k][n], bf16 hi (+ lo for Wq,Wk).
// ---------------------------------------------------------------------------
__global__ __launch_bounds__(256) void transpose_split4(
    const float* __restrict__ Wq, const float* __restrict__ Wk,
    const float* __restrict__ Wv, const float* __restrict__ Wo,
    short* __restrict__ Tqh, short* __restrict__ Tql,
    short* __restrict__ Tkh, short* __restrict__ Tkl,
    short* __restrict__ Tvh, short* __restrict__ Toh) {
    const int z = blockIdx.z;
    const float* W = (z == 0) ? Wq : (z == 1) ? Wk : (z == 2) ? Wv : Wo;
    short* Thi = (z == 0) ? Tqh : (z == 1) ? Tkh : (z == 2) ? Tvh : Toh;
    short* Tlo = (z == 0) ? Tql : (z == 1) ? Tkl : nullptr;

    __shared__ float tile[32][33];
    const int tx = threadIdx.x & 31, ty = threadIdx.x >> 5;
    const int k0 = blockIdx.x * 32, n0 = blockIdx.y * 32;
#pragma unroll
    for (int p = 0; p < 4; ++p)
        tile[ty + p * 8][tx] = W[(size_t)(k0 + ty + p * 8) * 1024 + n0 + tx];
    __syncthreads();
#pragma unroll
    for (int p = 0; p < 4; ++p) {
        int n = n0 + ty + p * 8, k = k0 + tx;
        float x = tile[tx][ty + p * 8];
        short h = f2bf(x);
        Thi[(size_t)n * 1024 + k] = h;
        if (Tlo) Tlo[(size_t)n * 1024 + k] = f2bf(x - bf2f(h));
    }
}

// ---------------------------------------------------------------------------
// Fused fp32 -> bf16 hi (+ lo) splits: z selects {q,k,v}.  8 elems/thread.
// ---------------------------------------------------------------------------
__global__ __launch_bounds__(256) void split3(
    const float* __restrict__ q, const float* __restrict__ k,
    const float* __restrict__ v,
    short* __restrict__ Qhi, short* __restrict__ Qlo,
    short* __restrict__ Khi, short* __restrict__ Klo,
    short* __restrict__ Vbf) {
    const int z = blockIdx.z;
    const float* X = (z == 0) ? q : (z == 1) ? k : v;
    short* Hi = (z == 0) ? Qhi : (z == 1) ? Khi : Vbf;
    short* Lo = (z == 0) ? Qlo : (z == 1) ? Klo : nullptr;
    const int n8 = (z == 2) ? (4094 * 1024 / 8) : (4096 * 1024 / 8);

    int idx = blockIdx.x * 256 + threadIdx.x;
    if (idx >= n8) return;
    float4 x0 = *((const float4*)X + (size_t)idx * 2);
    float4 x1 = *((const float4*)X + (size_t)idx * 2 + 1);
    float xs[8] = {x0.x, x0.y, x0.z, x0.w, x1.x, x1.y, x1.z, x1.w};
    bf16x8 hv, lv;
#pragma unroll
    for (int e = 0; e < 8; ++e) {
        short h = f2bf(xs[e]);
        hv[e] = h;
        lv[e] = f2bf(xs[e] - bf2f(h));
    }
    *(bf16x8*)&Hi[(size_t)idx * 8] = hv;
    if (Lo) *(bf16x8*)&Lo[(size_t)idx * 8] = lv;
}

// ---------------------------------------------------------------------------
// Merged Q/K/V projection GEMM, 128x128 tile.  blockIdx.z selects {Q,K,V}.
// C[M x 1024] = A[M x 1024] @ Bt^T + bias  (Bt[n][k] pre-transposed).
// BK=32, 256 thr / 4 waves; wave quadrant 64x64 = 4x4 frags of 16x16x32
// -> 16 MFMA (48 split) per K-step per wave.  A and B both staged via
// global_load_lds, chunk-major [cc=4][row=128] (lane-linear DMA,
// conflict-free ds_read_b128).  LDS 32KB (split) / 16KB (V).
// ---------------------------------------------------------------------------
__global__ __launch_bounds__(256) void gemm_qkv(
    const short* __restrict__ Qhi, const short* __restrict__ Qlo,
    const short* __restrict__ Khi, const short* __restrict__ Klo,
    const short* __restrict__ Vbf,
    const short* __restrict__ Wqh, const short* __restrict__ Wql,
    const short* __restrict__ Wkh, const short* __restrict__ Wkl,
    const short* __restrict__ Wvh,
    const float* __restrict__ bq, const float* __restrict__ bk,
    const float* __restrict__ bv, float qscale,
    short* __restrict__ QQh, short* __restrict__ QQl,
    short* __restrict__ KKh, short* __restrict__ KKl,
    short* __restrict__ VVo) {
    __shared__ __align__(16) short Ah[512 * 8];   // [cc=4][row=128]
    __shared__ __align__(16) short Al[512 * 8];
    __shared__ __align__(16) short Bh[512 * 8];
    __shared__ __align__(16) short Bl[512 * 8];

    const int z = blockIdx.z;
    const bool split = (z < 2);
    const short* Ahg = (z == 0) ? Qhi : ((z == 1) ? Khi : Vbf);
    const short* Alg = (z == 0) ? Qlo : Klo;
    const short* Bhg = (z == 0) ? Wqh : ((z == 1) ? Wkh : Wvh);
    const short* Blg = (z == 0) ? Wql : Wkl;
    const float* bias = (z == 0) ? bq : ((z == 1) ? bk : bv);
    const float scale = (z == 0) ? qscale : 1.0f;
    const int M = (z == 2) ? 4094 : 4096;
    short* Chi = (z == 0) ? QQh : ((z == 1) ? KKh : VVo);
    short* Clo = (z == 0) ? QQl : KKl;

    const int tid = threadIdx.x;
    const int w = tid >> 6, lane = tid & 63;
    const int quad = lane >> 4, l16 = lane & 15;
    const int m0 = blockIdx.y * 128, n0 = blockIdx.x * 128;
    const int wr = (w & 1) * 64, wc = (w >> 1) * 64;

    f32x4 acc[4][4];
#pragma unroll
    for (int mi = 0; mi < 4; ++mi)
#pragma unroll
        for (int ni = 0; ni < 4; ++ni) acc[mi][ni] = (f32x4){0.f, 0.f, 0.f, 0.f};

    const int a_gr = imin(m0 + (tid & 127), M - 1);
    const int b_gr = n0 + (tid & 127);

    for (int k0 = 0; k0 < 1024; k0 += 32) {
        __syncthreads();
#pragma unroll
        for (int p = 0; p < 2; ++p) {
            const int idx = p * 256 + tid;            // cc = idx>>7, row = idx&127
            const size_t ga = (size_t)a_gr * 1024 + k0 + (idx >> 7) * 8;
            const size_t gb = (size_t)b_gr * 1024 + k0 + (idx >> 7) * 8;
            dma16(Ahg + ga, &Ah[idx * 8]);
            dma16(Bhg + gb, &Bh[idx * 8]);
            if (split) {
                dma16(Alg + ga, &Al[idx * 8]);
                dma16(Blg + gb, &Bl[idx * 8]);
            }
        }
        __syncthreads();

        bf16x8 af[4], afl[4];
#pragma unroll
        for (int mi = 0; mi < 4; ++mi) {
            const int r = wr + mi * 16 + l16;
            af[mi] = *(const bf16x8*)&Ah[(quad * 128 + r) * 8];
            if (split) afl[mi] = *(const bf16x8*)&Al[(quad * 128 + r) * 8];
        }
#pragma unroll
        for (int ni = 0; ni < 4; ++ni) {
            const int cdx = wc + ni * 16 + l16;
            const bf16x8 bfh = *(const bf16x8*)&Bh[(quad * 128 + cdx) * 8];
#pragma unroll
            for (int mi = 0; mi < 4; ++mi)
                acc[mi][ni] = MFMA_BF16(af[mi], bfh, acc[mi][ni]);
            if (split) {
                const bf16x8 bfl = *(const bf16x8*)&Bl[(quad * 128 + cdx) * 8];
#pragma unroll
                for (int mi = 0; mi < 4; ++mi) {
                    acc[mi][ni] = MFMA_BF16(af[mi], bfl, acc[mi][ni]);
                    acc[mi][ni] = MFMA_BF16(afl[mi], bfh, acc[mi][ni]);
                }
            }
        }
    }

#pragma unroll
    for (int ni = 0; ni < 4; ++ni) {
        const int col = n0 + wc + ni * 16 + l16;
        const float bv_ = bias[col];
#pragma unroll
        for (int mi = 0; mi < 4; ++mi) {
#pragma unroll
            for (int r = 0; r < 4; ++r) {
                const int row = m0 + wr + mi * 16 + quad * 4 + r;
                if (row < M) {
                    const float c = (acc[mi][ni][r] + bv_) * scale;
                    const size_t off = (size_t)row * 1024 + col;
                    const short hsv = f2bf(c);
                    Chi[off] = hsv;
                    if (split) Clo[off] = f2bf(c - bf2f(hsv));
                }
            }
        }
    }
}

// ---------------------------------------------------------------------------
// O-projection GEMM, 128x128 tile, fp32 out.
// ---------------------------------------------------------------------------
__global__ __launch_bounds__(256) void gemm_o(
    const short* __restrict__ Ahg, int M, const short* __restrict__ Bhg,
    const float* __restrict__ bias, float* __restrict__ Cf) {
    __shared__ __align__(16) short Ah[512 * 8];
    __shared__ __align__(16) short Bh[512 * 8];

    const int tid = threadIdx.x;
    const int w = tid >> 6, lane = tid & 63;
    const int quad = lane >> 4, l16 = lane & 15;
    const int m0 = blockIdx.y * 128, n0 = blockIdx.x * 128;
    const int wr = (w & 1) * 64, wc = (w >> 1) * 64;

    f32x4 acc[4][4];
#pragma unroll
    for (int mi = 0; mi < 4; ++mi)
#pragma unroll
        for (int ni = 0; ni < 4; ++ni) acc[mi][ni] = (f32x4){0.f, 0.f, 0.f, 0.f};

    const int a_gr = imin(m0 + (tid & 127), M - 1);
    const int b_gr = n0 + (tid & 127);

    for (int k0 = 0; k0 < 1024; k0 += 32) {
        __syncthreads();
#pragma unroll
        for (int p = 0; p < 2; ++p) {
            const int idx = p * 256 + tid;
            dma16(Ahg + (size_t)a_gr * 1024 + k0 + (idx >> 7) * 8, &Ah[idx * 8]);
            dma16(Bhg + (size_t)b_gr * 1024 + k0 + (idx >> 7) * 8, &Bh[idx * 8]);
        }
        __syncthreads();

        bf16x8 af[4];
#pragma unroll
        for (int mi = 0; mi < 4; ++mi)
            af[mi] = *(const bf16x8*)&Ah[(quad * 128 + wr + mi * 16 + l16) * 8];
#pragma unroll
        for (int ni = 0; ni < 4; ++ni) {
            const bf16x8 bfh = *(const bf16x8*)&Bh[(quad * 128 + wc + ni * 16 + l16) * 8];
#pragma unroll
            for (int mi = 0; mi < 4; ++mi)
                acc[mi][ni] = MFMA_BF16(af[mi], bfh, acc[mi][ni]);
        }
    }

#pragma unroll
    for (int ni = 0; ni < 4; ++ni) {
        const int col = n0 + wc + ni * 16 + l16;
        const float bv_ = bias[col];
#pragma unroll
        for (int mi = 0; mi < 4; ++mi)
#pragma unroll
            for (int r = 0; r < 4; ++r) {
                const int row = m0 + wr + mi * 16 + quad * 4 + r;
                if (row < M) Cf[(size_t)row * 1024 + col] = acc[mi][ni][r] + bv_;
            }
    }
}

// ---------------------------------------------------------------------------
// VV [ (b*2047+seq)*1024 + h*64 + d ] -> VT [ ((b*16+h)*64+d)*2048 + seq ]
// (row pad to 2048; pad col written as 0)
// ---------------------------------------------------------------------------
__global__ __launch_bounds__(256) void transpose_v_kernel(
    const short* __restrict__ VV, short* __restrict__ VT) {
    __shared__ short t[64][72];
    const int tid = threadIdx.x;
    const int st = blockIdx.x & 31, bh = blockIdx.x >> 5;
    const int b = bh >> 4, h = bh & 15;
    const int s0 = st * 64;
    {
        int seq = s0 + (tid >> 2), d0 = (tid & 3) * 16;
        int seqc = imin(seq, 2046);
        const short* src = VV + ((size_t)(b * 2047 + seqc)) * 1024 + h * 64 + d0;
        bf16x8 v0 = *(const bf16x8*)src;
        bf16x8 v1 = *(const bf16x8*)(src + 8);
        bool ok = (seq <= 2046);
#pragma unroll
        for (int e = 0; e < 8; ++e) {
            t[d0 + e][tid >> 2] = ok ? v0[e] : (short)0;
            t[d0 + 8 + e][tid >> 2] = ok ? v1[e] : (short)0;
        }
    }
    __syncthreads();
    {
        int d = tid >> 2, sc2 = (tid & 3) * 16;
        bf16x8 o0, o1;
#pragma unroll
        for (int e = 0; e < 8; ++e) {
            o0[e] = t[d][sc2 + e];
            o1[e] = t[d][sc2 + 8 + e];
        }
        short* dst = VT + ((size_t)(bh * 64 + d)) * 2048 + s0 + sc2;
        *(bf16x8*)dst = o0;
        *(bf16x8*)(dst + 8) = o1;
    }
}

// ---------------------------------------------------------------------------
// Fused causal attention (unchanged from R3).  128 q-rows / block (8 waves).
// Pass A: denominators, K-hi dbuf via Kh/Kl, 1 barrier/tile.
// Pass B: hi/lo K + V staged, 2 barriers/tile, att writes + PV.
// ---------------------------------------------------------------------------
__global__ __launch_bounds__(512) void attn_kernel(
    const short* __restrict__ QQh, const short* __restrict__ QQl,
    const short* __restrict__ KKh, const short* __restrict__ KKl,
    const short* __restrict__ VT,
    float* __restrict__ att, short* __restrict__ CTX) {
    __shared__ __align__(16) short Kh[512 * 8];   // [cc=8][key=64]
    __shared__ __align__(16) short Kl[512 * 8];   // pass A: 2nd buffer
    __shared__ __align__(16) short Vt[512 * 8];   // [kc=8][d=64]
    __shared__ __align__(16) short Ps[8][16 * 72];

    const int tid = threadIdx.x;
    const int w = tid >> 6, lane = tid & 63;
    const int quad = lane >> 4, l16 = lane & 15;
    const int bx = blockIdx.x;
    const int qt = 15 - (bx >> 5);          // heavy q-tiles first
    const int bh = bx & 31;
    const int h = bh & 15, b = bh >> 4;
    const int i0 = qt * 128;

    const int i_frag = i0 + w * 16 + l16;
    const int qrow = imin(i_frag + 1, 2047);
    const size_t qoff = ((size_t)(b * 2048 + qrow)) * 1024 + h * 64;
    const bf16x8 qh0 = *(const bf16x8*)&QQh[qoff + 0 + quad * 8];
    const bf16x8 qh1 = *(const bf16x8*)&QQh[qoff + 32 + quad * 8];
    const bf16x8 ql0 = *(const bf16x8*)&QQl[qoff + 0 + quad * 8];
    const bf16x8 ql1 = *(const bf16x8*)&QQl[qoff + 32 + quad * 8];

    const int i_max = imin(i0 + 127, 2046);
    const int jt_max = i_max >> 6;
    const int wave_imax = imin(i0 + w * 16 + 15, 2046);
    const int rowbase = i0 + w * 16 + quad * 4;

    const int dk = tid & 63;     // key (K) / dim (V) row
    const int dc = tid >> 6;     // 8-elem chunk

    float lsum[4] = {0.f, 0.f, 0.f, 0.f};

    // ---------------- PASS A: softmax denominators (K-hi only) --------------
    auto stA = [&](int jt, short* dst) {
        dma16(KKh + ((size_t)(b * 2048 + jt * 64 + dk)) * 1024 + h * 64 + dc * 8,
              &dst[tid * 8]);
    };
    stA(0, Kh);
    __syncthreads();
    int cur = 0;
    for (int jt = 0; jt <= jt_max; ++jt) {
        if (jt < jt_max) stA(jt + 1, cur ? Kh : Kl);
        if (jt * 64 <= wave_imax) {
            const short* Kc = cur ? Kl : Kh;
#pragma unroll
            for (int s = 0; s < 4; ++s) {
                f32x4 sc = (f32x4){0.f, 0.f, 0.f, 0.f};
#pragma unroll
                for (int c = 0; c < 2; ++c) {
                    bf16x8 kh = *(const bf16x8*)&Kc[((c * 4 + quad) * 64 + s * 16 + l16) * 8];
                    sc = MFMA_BF16(c ? qh1 : qh0, kh, sc);
                    sc = MFMA_BF16(c ? ql1 : ql0, kh, sc);
                }
                int j = jt * 64 + s * 16 + l16;
#pragma unroll
                for (int r = 0; r < 4; ++r) {
                    int i = rowbase + r;
                    if (j <= i && i <= 2046) lsum[r] += fexp2(sc[r]);
                }
            }
        }
        __syncthreads();
        cur ^= 1;
    }
#pragma unroll
    for (int m = 1; m < 16; m <<= 1) {
#pragma unroll
        for (int r = 0; r < 4; ++r) lsum[r] += __shfl_xor(lsum[r], m, 64);
    }
    float linv[4];
#pragma unroll
    for (int r = 0; r < 4; ++r) linv[r] = 1.0f / lsum[r];

    f32x4 cacc[4];
#pragma unroll
    for (int t = 0; t < 4; ++t) cacc[t] = (f32x4){0.f, 0.f, 0.f, 0.f};

    // ---------------- PASS B: att writes + PV -------------------------------
    for (int jt = 0; jt <= jt_max; ++jt) {
        const int j0 = jt * 64;
        __syncthreads();   // previous tile fully consumed
        {
            const size_t ko = ((size_t)(b * 2048 + j0 + dk)) * 1024 + h * 64 + dc * 8;
            dma16(KKh + ko, &Kh[tid * 8]);
            dma16(KKl + ko, &Kl[tid * 8]);
            dma16(VT + ((size_t)(bh * 64 + dk)) * 2048 + j0 + dc * 8, &Vt[tid * 8]);
        }
        __syncthreads();   // drain DMA
        if (j0 <= wave_imax) {
#pragma unroll
            for (int s = 0; s < 4; ++s) {
                f32x4 sc = (f32x4){0.f, 0.f, 0.f, 0.f};
#pragma unroll
                for (int c = 0; c < 2; ++c) {
                    const int ci = ((c * 4 + quad) * 64 + s * 16 + l16) * 8;
                    bf16x8 kh = *(const bf16x8*)&Kh[ci];
                    bf16x8 kl = *(const bf16x8*)&Kl[ci];
                    bf16x8 ah = c ? qh1 : qh0;
                    bf16x8 al = c ? ql1 : ql0;
                    sc = MFMA_BF16(ah, kh, sc);
                    sc = MFMA_BF16(ah, kl, sc);
                    sc = MFMA_BF16(al, kh, sc);
                }
                int j = j0 + s * 16 + l16;
#pragma unroll
                for (int r = 0; r < 4; ++r) {
                    int i = rowbase + r;
                    bool valid = (j <= i) && (i <= 2046);
                    float p = valid ? fexp2(sc[r]) * linv[r] : 0.0f;
                    if (i <= 2046 && j <= 2046)
                        att[((size_t)bh * 2047 + i) * 2047 + j] = p;
                    Ps[w][(quad * 4 + r) * 72 + s * 16 + l16] = f2bf(p);
                }
            }
#pragma unroll
            for (int c = 0; c < 2; ++c) {
                bf16x8 pa = *(const bf16x8*)&Ps[w][l16 * 72 + c * 32 + quad * 8];
#pragma unroll
                for (int t = 0; t < 4; ++t) {
                    bf16x8 vb = *(const bf16x8*)&Vt[((c * 4 + quad) * 64 + t * 16 + l16) * 8];
                    cacc[t] = MFMA_BF16(pa, vb, cacc[t]);
                }
            }
        } else {
#pragma unroll
            for (int s = 0; s < 4; ++s) {
                int j = j0 + s * 16 + l16;
#pragma unroll
                for (int r = 0; r < 4; ++r) {
                    int i = rowbase + r;
                    if (i <= 2046 && j <= 2046)
                        att[((size_t)bh * 2047 + i) * 2047 + j] = 0.0f;
                }
            }
        }
    }

    // ctx -> CTX (bf16)
#pragma unroll
    for (int t = 0; t < 4; ++t) {
#pragma unroll
        for (int r = 0; r < 4; ++r) {
            int i = rowbase + r;
            if (i <= 2046)
                CTX[((size_t)(b * 2047 + i)) * 1024 + h * 64 + t * 16 + l16] = f2bf(cacc[t][r]);
        }
    }

    // zero tail: att cols beyond the block's causal tiles (float4 vectorized)
    const int js = (jt_max + 1) * 64;
    if (js < 2047) {
        const float4 z4 = {0.f, 0.f, 0.f, 0.f};
        for (int i = i0; i <= i_max; ++i) {
            const size_t base = (size_t)(bh * 2047 + i) * 2047;
            float* rowp = att + base;
            int aligned = js + (int)((4 - ((base + js) & 3)) & 3);
            if (aligned > 2047) aligned = 2047;
            for (int c = js + tid; c < aligned; c += 512) rowp[c] = 0.0f;
            int nv = (2047 - aligned) >> 2;
            for (int q = tid; q < nv; q += 512)
                *(float4*)(rowp + aligned + q * 4) = z4;
            for (int c = aligned + nv * 4 + tid; c < 2047; c += 512) rowp[c] = 0.0f;
        }
    }
}

// ---------------------------------------------------------------------------
extern "C" void kernel_launch(void* const* d_in, const int* in_sizes, int n_in,
                              void* d_out, int out_size, void* d_ws, size_t ws_size,
                              hipStream_t stream) {
    (void)in_sizes; (void)n_in; (void)out_size; (void)ws_size;
    const float* q  = (const float*)d_in[0];
    const float* k  = (const float*)d_in[1];
    const float* v  = (const float*)d_in[2];
    const float* Wq = (const float*)d_in[4];
    const float* bq = (const float*)d_in[5];
    const float* Wk = (const float*)d_in[6];
    const float* bk = (const float*)d_in[7];
    const float* Wv = (const float*)d_in[8];
    const float* bv = (const float*)d_in[9];
    const float* Wo = (const float*)d_in[10];
    const float* bo = (const float*)d_in[11];

    float* out = (float*)d_out;                     // 2*2047*1024
    float* att = out + (size_t)2 * 2047 * 1024;     // 2*16*2047*2047

    char* ws = (char*)d_ws;
    size_t off = 0;
    auto alloc = [&](size_t bytes) -> void* {
        void* p = ws + off;
        off += (bytes + 255) & ~(size_t)255;
        return p;
    };
    short* Wqt_h = (short*)alloc((size_t)1024 * 1024 * 2);
    short* Wqt_l = (short*)alloc((size_t)1024 * 1024 * 2);
    short* Wkt_h = (short*)alloc((size_t)1024 * 1024 * 2);
    short* Wkt_l = (short*)alloc((size_t)1024 * 1024 * 2);
    short* Wvt_h = (short*)alloc((size_t)1024 * 1024 * 2);
    short* Wot_h = (short*)alloc((size_t)1024 * 1024 * 2);
    short* Qhi = (short*)alloc((size_t)4096 * 1024 * 2);
    short* Qlo = (short*)alloc((size_t)4096 * 1024 * 2);
    short* Khi = (short*)alloc((size_t)4096 * 1024 * 2);
    short* Klo = (short*)alloc((size_t)4096 * 1024 * 2);
    short* Vbf = (short*)alloc((size_t)4096 * 1024 * 2);
    short* QQh = (short*)alloc((size_t)4096 * 1024 * 2);
    short* QQl = (short*)alloc((size_t)4096 * 1024 * 2);
    short* KKh = (short*)alloc((size_t)4096 * 1024 * 2);
    short* KKl = (short*)alloc((size_t)4096 * 1024 * 2);
    short* VV  = (short*)alloc((size_t)4096 * 1024 * 2);
    short* VT  = (short*)alloc((size_t)2048 * 2048 * 2 * 2);
    short* CTX = (short*)alloc((size_t)4096 * 1024 * 2);

    transpose_split4<<<dim3(32, 32, 4), 256, 0, stream>>>(
        Wq, Wk, Wv, Wo, Wqt_h, Wqt_l, Wkt_h, Wkt_l, Wvt_h, Wot_h);

    split3<<<dim3(2048, 1, 3), 256, 0, stream>>>(
        q, k, v, Qhi, Qlo, Khi, Klo, Vbf);

    // QQ scaled by log2(e)/8 so attention softmax can use native exp2.
    const float qscale = 0.125f * 1.44269504088896341f;
    gemm_qkv<<<dim3(8, 32, 3), 256, 0, stream>>>(
        Qhi, Qlo, Khi, Klo, Vbf, Wqt_h, Wqt_l, Wkt_h, Wkt_l, Wvt_h,
        bq, bk, bv, qscale, QQh, QQl, KKh, KKl, VV);

    transpose_v_kernel<<<dim3(32 * 32), 256, 0, stream>>>(VV, VT);

    attn_kernel<<<dim3(16 * 32), 512, 0, stream>>>(QQh, QQl, KKh, KKl, VT, att, CTX);

    gemm_o<<<dim3(8, 32), 256, 0, stream>>>(CTX, 4094, Wot_h, bo, out);
}